// Round 13
// baseline (221.012 us; speedup 1.0000x reference)
//
#include <hip/hip_runtime.h>
#include <math.h>

#define Bq 64
#define Tq 1024
#define Nq 128

typedef __attribute__((ext_vector_type(2))) _Float16 h2;

#if defined(__has_builtin)
#  if __has_builtin(__builtin_amdgcn_fdot2)
#    define HAVE_FDOT2 1
#  endif
#  if __has_builtin(__builtin_amdgcn_rcpf)
#    define HAVE_RCPF 1
#  endif
#endif

__device__ __forceinline__ float dot2acc(h2 a, h2 b, float c) {
#ifdef HAVE_FDOT2
    return __builtin_amdgcn_fdot2(a, b, c, false);
#else
    return c + (float)a.x * (float)b.x + (float)a.y * (float)b.y;
#endif
}

__device__ __forceinline__ float fastrcp(float x) {
#ifdef HAVE_RCPF
    return __builtin_amdgcn_rcpf(x);
#else
    return 1.0f / x;
#endif
}

union Q16 { int4 v; h2 p[4]; };

#define EXP_NEG7 9.118819655545162e-4f

// ---------------------------------------------------------------------------
// Pre-pass: eeh[i] = (f16) exp(emissions[i]).  exp(emit) in [~0.01, ~90],
// comfortably inside f16 range/precision. Memory-bound, ~8 us.
// ---------------------------------------------------------------------------
__global__ __launch_bounds__(256)
void crf_prepass_kernel(const float* __restrict__ em, _Float16* __restrict__ eeh) {
    const size_t i = ((size_t)blockIdx.x * 256 + threadIdx.x) * 16;
    const float4* src = (const float4*)(em + i);
    h2* dst = (h2*)(eeh + i);
    #pragma unroll
    for (int v = 0; v < 4; ++v) {
        float4 x = src[v];
        h2 a; a.x = (_Float16)__expf(x.x); a.y = (_Float16)__expf(x.y);
        h2 b; b.x = (_Float16)__expf(x.z); b.y = (_Float16)__expf(x.w);
        dst[2 * v]     = a;
        dst[2 * v + 1] = b;
    }
}

// ---------------------------------------------------------------------------
// One recursion step (R10/R12-proven numerics, direction-agnostic).
//   PRE=true : ee pipeline is 3-deep f16 loads from the warm eeh array,
//              issued FIRST after the barrier (max slack before next drain).
//   PRE=false: exact R12 behavior (5-deep raw f32 + in-loop expf + fence).
// ---------------------------------------------------------------------------
template<bool PRE>
__device__ __forceinline__ void step_core(
    int rawRow, int n, const float* __restrict__ em_n,
    const _Float16* __restrict__ eeh_n,
    const _Float16* __restrict__ rb, _Float16* __restrict__ wb,
    const h2 (&e)[64],
    float& ee0, float& ee1, float& ee2, float& raw3, float& raw4,
    float& Mcur, float& pOut, float& ssOut)
{
    __syncthreads();                       // rb fully written by both waves

    // issue the next emission fetch immediately (independent of everything)
    float ld;
    if (PRE) ld = (float)eeh_n[(size_t)rawRow * Nq];
    else     ld = em_n[(size_t)rawRow * Nq];

    const int4* p4 = (const int4*)rb;
    Q16 U[16];
    #pragma unroll
    for (int q = 0; q < 16; ++q) U[q].v = p4[q];     // broadcast reads
    if (!PRE) asm volatile("" ::: "memory");         // R12-proven ordering

    // sampled max of p[0..3] — identical in every lane (broadcast values)
    float pm = fmaxf(fmaxf((float)U[0].p[0].x, (float)U[0].p[0].y),
                     fmaxf((float)U[0].p[1].x, (float)U[0].p[1].y));
    pm = fmaxf(pm, 1e-6f);
    const float f = ee0 * (fastrcp(pm) * EXP_NEG7);

    float s[4] = {0.f, 0.f, 0.f, 0.f};
    #pragma unroll
    for (int j = 0; j < 64; ++j)                     // static after unroll
        s[j & 3] = dot2acc(U[j >> 2].p[j & 3], e[j], s[j & 3]);
    const float ss = (s[0] + s[1]) + (s[2] + s[3]);
    ssOut = ss;

    const float pn = fminf(ss * f, 60000.0f);
    wb[n] = (_Float16)pn;
    pOut = pn;

    // side chains (loop-carried only on themselves)
    Mcur += __logf(pm) + 7.0f;
    if (PRE) {
        ee0 = ee1; ee1 = ee2; ee2 = ld;
    } else {
        const float eeN = __expf(raw3);
        ee0 = ee1; ee1 = ee2; ee2 = eeN;
        raw3 = raw4; raw4 = ld;
    }
}

// ---------------------------------------------------------------------------
// Blocks 0..63:    forward half-chain  (t = 1 .. tm),   E-columns
// Blocks 64..127:  backward half-chain (t = tsz-1 .. tm+1), E-rows
// Blocks 128..191: gold-path score
// 128 threads; lane owns state n = tid.
// ---------------------------------------------------------------------------
template<bool PRE>
__global__ __launch_bounds__(128, 1)
void crf_main_kernel(const float* __restrict__ emissions,
                     const _Float16* __restrict__ eeh,
                     const int* __restrict__ token_sizes,
                     const int* __restrict__ targets,
                     const float* __restrict__ transitions,
                     const float* __restrict__ head,
                     const float* __restrict__ last,
                     float* __restrict__ wsW,
                     float* __restrict__ wsU,
                     float* __restrict__ wsMf,
                     float* __restrict__ wsMb,
                     float* __restrict__ out) {
    const int tid = threadIdx.x;
    const int bid = blockIdx.x;

    if (bid >= 2 * Bq) {
        // ---------------- score path ----------------
        const int b = bid - 2 * Bq;
        const int tsz = token_sizes[b];
        const int* tg = targets + b * Tq;
        const float* em = emissions + (size_t)b * Tq * Nq;
        float sc = 0.f;
        for (int t = tid; t < tsz; t += 128) {
            int cur = tg[t];
            sc += em[(size_t)t * Nq + cur];
            if (t >= 1) sc += transitions[tg[t - 1] * Nq + cur];
        }
        #pragma unroll
        for (int off = 32; off >= 1; off >>= 1)
            sc += __shfl_xor(sc, off, 64);
        __shared__ float wsum[2];
        if ((tid & 63) == 0) wsum[tid >> 6] = sc;
        __syncthreads();
        if (tid == 0)
            out[Bq + b] = wsum[0] + wsum[1] + head[tg[0]] + last[tg[tsz - 1]];
        return;
    }

    const bool isFwd = (bid < Bq);
    const int b = isFwd ? bid : (bid - Bq);
    const int n = tid;
    const int wv = tid >> 6;
    const int l = tid & 63;
    const float* em_c = emissions + (size_t)b * Tq * Nq;
    const float* em_n = em_c + n;
    const _Float16* eeh_n = PRE ? (eeh + (size_t)b * Tq * Nq + n) : (const _Float16*)nullptr;
    const int tsz = token_sizes[b];      // in [T/2, T]
    const int tm = tsz >> 1;             // split point

    __shared__ __align__(16) _Float16 pbuf[2][Nq];
    __shared__ float redA[2];

    // E fragments: forward = column n of E; backward = row n of E.
    h2 e[64];
    if (isFwd) {
        #pragma unroll
        for (int j = 0; j < 64; ++j) {
            h2 v;
            v.x = (_Float16)__expf(transitions[(2 * j)     * Nq + n]);
            v.y = (_Float16)__expf(transitions[(2 * j + 1) * Nq + n]);
            e[j] = v;
        }
    } else {
        #pragma unroll
        for (int j = 0; j < 64; ++j) {
            h2 v;
            v.x = (_Float16)__expf(transitions[n * Nq + 2 * j]);
            v.y = (_Float16)__expf(transitions[n * Nq + 2 * j + 1]);
            e[j] = v;
        }
    }
    #pragma unroll
    for (int j = 0; j < 64; ++j) asm volatile("" : "+v"(e[j]));

    // init vector (log domain) + uniform M0 via block reduce
    const float v0 = isFwd ? (head[n] + em_n[0])
                           : (last[n] + em_n[(size_t)(tsz - 1) * Nq]);
    float Mcur;
    {
        float w = v0;
        #pragma unroll
        for (int off = 32; off >= 1; off >>= 1)
            w = fmaxf(w, __shfl_xor(w, off, 64));
        if (l == 0) redA[wv] = w;
        __syncthreads();
        Mcur = fmaxf(redA[0], redA[1]);
    }
    pbuf[0][n] = (_Float16)__expf(v0 - Mcur);   // in (0,1]

    const int nsteps = isFwd ? tm : (tsz - 1 - tm);   // >= 255

    // emission pipeline init
    float ee0, ee1, ee2, raw3 = 0.f, raw4 = 0.f;
    if (PRE) {
        if (isFwd) {
            ee0 = (float)eeh_n[1 * Nq];
            ee1 = (float)eeh_n[2 * Nq];
            ee2 = (float)eeh_n[3 * Nq];
        } else {
            ee0 = (float)eeh_n[(size_t)(tsz - 2) * Nq];
            ee1 = (float)eeh_n[(size_t)(tsz - 3) * Nq];
            ee2 = (float)eeh_n[(size_t)(tsz - 4) * Nq];
        }
    } else {
        if (isFwd) {
            ee0 = __expf(em_n[1 * Nq]);
            ee1 = __expf(em_n[2 * Nq]);
            ee2 = __expf(em_n[3 * Nq]);
            raw3 = em_n[4 * Nq];
            raw4 = em_n[5 * Nq];
        } else {
            ee0 = __expf(em_n[(size_t)(tsz - 2) * Nq]);
            ee1 = __expf(em_n[(size_t)(tsz - 3) * Nq]);
            ee2 = __expf(em_n[(size_t)(tsz - 4) * Nq]);
            raw3 = em_n[(size_t)(tsz - 5) * Nq];
            raw4 = em_n[(size_t)(tsz - 6) * Nq];
        }
    }

    float pOut = 0.f, ssOut = 0.f, Msave = Mcur;
    _Float16* b0 = &pbuf[0][0];
    _Float16* b1 = &pbuf[1][0];

    // row fetched by body k (consumed PRE ? 3 : 5 bodies later)
    #define RAW_ROW(k) (PRE ? (isFwd ? min((k) + 3, tsz - 1) : max(tsz - 4 - (k), 0)) \
                            : (isFwd ? min((k) + 5, tsz - 1) : max(tsz - 6 - (k), 0)))

    int k = 1;
    for (; k + 3 <= nsteps; k += 4) {
        Msave = Mcur;
        step_core<PRE>(RAW_ROW(k),     n, em_n, eeh_n, b0, b1, e, ee0, ee1, ee2, raw3, raw4, Mcur, pOut, ssOut);
        Msave = Mcur;
        step_core<PRE>(RAW_ROW(k + 1), n, em_n, eeh_n, b1, b0, e, ee0, ee1, ee2, raw3, raw4, Mcur, pOut, ssOut);
        Msave = Mcur;
        step_core<PRE>(RAW_ROW(k + 2), n, em_n, eeh_n, b0, b1, e, ee0, ee1, ee2, raw3, raw4, Mcur, pOut, ssOut);
        Msave = Mcur;
        step_core<PRE>(RAW_ROW(k + 3), n, em_n, eeh_n, b1, b0, e, ee0, ee1, ee2, raw3, raw4, Mcur, pOut, ssOut);
    }
    if (k <= nsteps) {
        Msave = Mcur;
        step_core<PRE>(RAW_ROW(k), n, em_n, eeh_n, b0, b1, e, ee0, ee1, ee2, raw3, raw4, Mcur, pOut, ssOut);
        ++k;
        if (k <= nsteps) {
            Msave = Mcur;
            step_core<PRE>(RAW_ROW(k), n, em_n, eeh_n, b1, b0, e, ee0, ee1, ee2, raw3, raw4, Mcur, pOut, ssOut);
            ++k;
            if (k <= nsteps) {
                Msave = Mcur;
                step_core<PRE>(RAW_ROW(k), n, em_n, eeh_n, b0, b1, e, ee0, ee1, ee2, raw3, raw4, Mcur, pOut, ssOut);
            }
        }
    }
    #undef RAW_ROW

    if (isFwd) {
        wsW[b * Nq + n] = pOut;                 // pairs with post-update ledger
        if (tid == 0) wsMf[b] = Mcur;
    } else {
        wsU[b * Nq + n] = ssOut;                // pairs with pre-update ledger
        if (tid == 0) wsMb[b] = Msave;
    }
}

// ---------------------------------------------------------------------------
// Combine: out[b] = log( sum_n w_tm[n] * beta[n] ) + Mf + Mb
// ---------------------------------------------------------------------------
__global__ __launch_bounds__(64)
void crf_combine_kernel(const float* __restrict__ wsW,
                        const float* __restrict__ wsU,
                        const float* __restrict__ wsMf,
                        const float* __restrict__ wsMb,
                        float* __restrict__ out) {
    const int b = blockIdx.x;
    const int l = threadIdx.x;
    const float* w = wsW + b * Nq;
    const float* u = wsU + b * Nq;
    float z = w[l] * u[l] + w[l + 64] * u[l + 64];
    #pragma unroll
    for (int off = 32; off >= 1; off >>= 1)
        z += __shfl_xor(z, off, 64);
    if (l == 0) out[b] = __logf(z) + wsMf[b] + wsMb[b];
}

extern "C" void kernel_launch(void* const* d_in, const int* in_sizes, int n_in,
                              void* d_out, int out_size, void* d_ws, size_t ws_size,
                              hipStream_t stream) {
    const float* emissions   = (const float*)d_in[0];
    const int*   token_sizes = (const int*)d_in[1];
    const int*   targets     = (const int*)d_in[2];
    const float* transitions = (const float*)d_in[3];  // (1,1,128,128)
    const float* head        = (const float*)d_in[4];  // (1,1,128)
    const float* last        = (const float*)d_in[5];  // (1,1,128)
    float* out = (float*)d_out;                        // (2,64,1) flat

    const size_t eeBytes   = (size_t)Bq * Tq * Nq * sizeof(_Float16);  // 16.78 MB
    const size_t tailBytes = (size_t)(2 * Bq * Nq + 2 * Bq) * sizeof(float);
    const bool pre = (ws_size >= eeBytes + tailBytes);

    _Float16* eeh;
    float* wsW;
    if (pre) {
        eeh = (_Float16*)d_ws;
        wsW = (float*)((char*)d_ws + eeBytes);
    } else {
        eeh = nullptr;
        wsW = (float*)d_ws;
    }
    float* wsU  = wsW + Bq * Nq;
    float* wsMf = wsU + Bq * Nq;
    float* wsMb = wsMf + Bq;

    if (pre) {
        crf_prepass_kernel<<<2048, 256, 0, stream>>>(emissions, eeh);
        crf_main_kernel<true><<<3 * Bq, 128, 0, stream>>>(
            emissions, eeh, token_sizes, targets, transitions, head, last,
            wsW, wsU, wsMf, wsMb, out);
    } else {
        crf_main_kernel<false><<<3 * Bq, 128, 0, stream>>>(
            emissions, eeh, token_sizes, targets, transitions, head, last,
            wsW, wsU, wsMf, wsMb, out);
    }
    crf_combine_kernel<<<Bq, 64, 0, stream>>>(wsW, wsU, wsMf, wsMb, out);
}

// Round 14
// 178.255 us; speedup vs baseline: 1.2399x; 1.2399x over previous
//
#include <hip/hip_runtime.h>
#include <math.h>

#define Bq 64
#define Tq 1024
#define Nq 128

typedef __attribute__((ext_vector_type(2))) _Float16 h2;

#if defined(__has_builtin)
#  if __has_builtin(__builtin_amdgcn_fdot2)
#    define HAVE_FDOT2 1
#  endif
#  if __has_builtin(__builtin_amdgcn_rcpf)
#    define HAVE_RCPF 1
#  endif
#endif

__device__ __forceinline__ float dot2acc(h2 a, h2 b, float c) {
#ifdef HAVE_FDOT2
    return __builtin_amdgcn_fdot2(a, b, c, false);
#else
    return c + (float)a.x * (float)b.x + (float)a.y * (float)b.y;
#endif
}

__device__ __forceinline__ float fastrcp(float x) {
#ifdef HAVE_RCPF
    return __builtin_amdgcn_rcpf(x);
#else
    return 1.0f / x;
#endif
}

union Q16 { int4 v; h2 p[4]; };

#define EXP_NEG7 9.118819655545162e-4f

// ---------------------------------------------------------------------------
// One recursion step (R12-proven numerics, direction-agnostic).
// ONLY change vs R12: the emission load is issued FIRST after the barrier
// (above the p-reads and the fence), giving it the whole step body (~600 cyc)
// of slack before the next barrier's vmcnt(0) drain. The loaded f32 is not
// touched for 3 more steps (expf(raw3) side chain), so no early waitcnt.
// ---------------------------------------------------------------------------
__device__ __forceinline__ void step_core(
    int rawRow, int n, const float* __restrict__ em_n,
    const _Float16* __restrict__ rb, _Float16* __restrict__ wb,
    const h2 (&e)[64],
    float& ee0, float& ee1, float& ee2, float& raw3, float& raw4,
    float& Mcur, float& pOut, float& ssOut)
{
    __syncthreads();                       // rb fully written

    // issue emission load for a step 5 ahead — maximum slack to next barrier
    const float raw5 = em_n[(size_t)rawRow * Nq];

    const int4* p4 = (const int4*)rb;
    Q16 U[16];
    #pragma unroll
    for (int q = 0; q < 16; ++q) U[q].v = p4[q];     // broadcast reads
    asm volatile("" ::: "memory");         // keep wb store below the reads

    // sampled max of p[0..3] — identical in every lane (broadcast values)
    float pm = fmaxf(fmaxf((float)U[0].p[0].x, (float)U[0].p[0].y),
                     fmaxf((float)U[0].p[1].x, (float)U[0].p[1].y));
    pm = fmaxf(pm, 1e-6f);
    const float f = ee0 * (fastrcp(pm) * EXP_NEG7);

    float s[4] = {0.f, 0.f, 0.f, 0.f};
    #pragma unroll
    for (int j = 0; j < 64; ++j)                     // static after unroll
        s[j & 3] = dot2acc(U[j >> 2].p[j & 3], e[j], s[j & 3]);
    const float ss = (s[0] + s[1]) + (s[2] + s[3]);
    ssOut = ss;

    const float pn = fminf(ss * f, 60000.0f);
    wb[n] = (_Float16)pn;
    pOut = pn;

    // side chains (loop-carried only on themselves)
    Mcur += __logf(pm) + 7.0f;
    const float eeN = __expf(raw3);        // raw3 was loaded 3 steps ago
    ee0 = ee1; ee1 = ee2; ee2 = eeN;
    raw3 = raw4; raw4 = raw5;
}

// ---------------------------------------------------------------------------
// Blocks 0..63:    forward half-chain  (t = 1 .. tm),   E-columns
// Blocks 64..127:  backward half-chain (t = tsz-1 .. tm+1), E-rows
// Blocks 128..191: gold-path score
// 128 threads; lane owns state n = tid. Workspace: w_tm, beta, Mf, Mb.
// ---------------------------------------------------------------------------
__global__ __launch_bounds__(128, 1)
void crf_kernel(const float* __restrict__ emissions,
                const int* __restrict__ token_sizes,
                const int* __restrict__ targets,
                const float* __restrict__ transitions,
                const float* __restrict__ head,
                const float* __restrict__ last,
                float* __restrict__ wsW,    // [64][128] forward w_tm
                float* __restrict__ wsU,    // [64][128] backward beta
                float* __restrict__ wsMf,   // [64]
                float* __restrict__ wsMb,   // [64]
                float* __restrict__ out) {
    const int tid = threadIdx.x;
    const int bid = blockIdx.x;

    if (bid >= 2 * Bq) {
        // ---------------- score path ----------------
        const int b = bid - 2 * Bq;
        const int tsz = token_sizes[b];
        const int* tg = targets + b * Tq;
        const float* em = emissions + (size_t)b * Tq * Nq;
        float sc = 0.f;
        for (int t = tid; t < tsz; t += 128) {
            int cur = tg[t];
            sc += em[(size_t)t * Nq + cur];
            if (t >= 1) sc += transitions[tg[t - 1] * Nq + cur];
        }
        #pragma unroll
        for (int off = 32; off >= 1; off >>= 1)
            sc += __shfl_xor(sc, off, 64);
        __shared__ float wsum[2];
        if ((tid & 63) == 0) wsum[tid >> 6] = sc;
        __syncthreads();
        if (tid == 0)
            out[Bq + b] = wsum[0] + wsum[1] + head[tg[0]] + last[tg[tsz - 1]];
        return;
    }

    const bool isFwd = (bid < Bq);
    const int b = isFwd ? bid : (bid - Bq);
    const int n = tid;
    const int wv = tid >> 6;
    const int l = tid & 63;
    const float* em_c = emissions + (size_t)b * Tq * Nq;
    const float* em_n = em_c + n;
    const int tsz = token_sizes[b];      // in [T/2, T]
    const int tm = tsz >> 1;             // split point

    __shared__ __align__(16) _Float16 pbuf[2][Nq];
    __shared__ float redA[2];

    // E fragments: forward = column n of E (exp(trans[m][n]));
    //              backward = row n of E (exp(trans[n][m])).
    h2 e[64];
    if (isFwd) {
        #pragma unroll
        for (int j = 0; j < 64; ++j) {
            h2 v;
            v.x = (_Float16)__expf(transitions[(2 * j)     * Nq + n]);
            v.y = (_Float16)__expf(transitions[(2 * j + 1) * Nq + n]);
            e[j] = v;
        }
    } else {
        #pragma unroll
        for (int j = 0; j < 64; ++j) {
            h2 v;
            v.x = (_Float16)__expf(transitions[n * Nq + 2 * j]);
            v.y = (_Float16)__expf(transitions[n * Nq + 2 * j + 1]);
            e[j] = v;
        }
    }
    #pragma unroll
    for (int j = 0; j < 64; ++j) asm volatile("" : "+v"(e[j]));

    // init vector (log domain) + uniform M0 via block reduce
    const float v0 = isFwd ? (head[n] + em_n[0])
                           : (last[n] + em_n[(size_t)(tsz - 1) * Nq]);
    float Mcur;
    {
        float w = v0;
        #pragma unroll
        for (int off = 32; off >= 1; off >>= 1)
            w = fmaxf(w, __shfl_xor(w, off, 64));
        if (l == 0) redA[wv] = w;
        __syncthreads();
        Mcur = fmaxf(redA[0], redA[1]);
    }
    pbuf[0][n] = (_Float16)__expf(v0 - Mcur);   // in (0,1]

    const int nsteps = isFwd ? tm : (tsz - 1 - tm);   // >= 255

    // emission pipeline: ee for first 3 bodies; raw for bodies 4,5
    float ee0, ee1, ee2, raw3, raw4;
    if (isFwd) {
        ee0 = __expf(em_n[1 * Nq]);
        ee1 = __expf(em_n[2 * Nq]);
        ee2 = __expf(em_n[3 * Nq]);
        raw3 = em_n[4 * Nq];
        raw4 = em_n[5 * Nq];
    } else {
        ee0 = __expf(em_n[(size_t)(tsz - 2) * Nq]);
        ee1 = __expf(em_n[(size_t)(tsz - 3) * Nq]);
        ee2 = __expf(em_n[(size_t)(tsz - 4) * Nq]);
        raw3 = em_n[(size_t)(tsz - 5) * Nq];
        raw4 = em_n[(size_t)(tsz - 6) * Nq];
    }

    float pOut = 0.f, ssOut = 0.f, Msave = Mcur;
    _Float16* b0 = &pbuf[0][0];
    _Float16* b1 = &pbuf[1][0];

    // raw row for body k
    #define RAW_ROW(k) (isFwd ? min((k) + 5, tsz - 1) : max(tsz - 6 - (k), 0))

    int k = 1;
    for (; k + 3 <= nsteps; k += 4) {
        Msave = Mcur;
        step_core(RAW_ROW(k),     n, em_n, b0, b1, e, ee0, ee1, ee2, raw3, raw4, Mcur, pOut, ssOut);
        Msave = Mcur;
        step_core(RAW_ROW(k + 1), n, em_n, b1, b0, e, ee0, ee1, ee2, raw3, raw4, Mcur, pOut, ssOut);
        Msave = Mcur;
        step_core(RAW_ROW(k + 2), n, em_n, b0, b1, e, ee0, ee1, ee2, raw3, raw4, Mcur, pOut, ssOut);
        Msave = Mcur;
        step_core(RAW_ROW(k + 3), n, em_n, b1, b0, e, ee0, ee1, ee2, raw3, raw4, Mcur, pOut, ssOut);
    }
    if (k <= nsteps) {
        Msave = Mcur;
        step_core(RAW_ROW(k), n, em_n, b0, b1, e, ee0, ee1, ee2, raw3, raw4, Mcur, pOut, ssOut);
        ++k;
        if (k <= nsteps) {
            Msave = Mcur;
            step_core(RAW_ROW(k), n, em_n, b1, b0, e, ee0, ee1, ee2, raw3, raw4, Mcur, pOut, ssOut);
            ++k;
            if (k <= nsteps) {
                Msave = Mcur;
                step_core(RAW_ROW(k), n, em_n, b0, b1, e, ee0, ee1, ee2, raw3, raw4, Mcur, pOut, ssOut);
            }
        }
    }
    #undef RAW_ROW

    if (isFwd) {
        // w_tm[n] = pOut * e^{Mcur}  (pOut pairs with post-update ledger)
        wsW[b * Nq + n] = pOut;
        if (tid == 0) wsMf[b] = Mcur;
    } else {
        // beta[n] = ssOut * e^{Msave} (ss pairs with pre-update ledger)
        wsU[b * Nq + n] = ssOut;
        if (tid == 0) wsMb[b] = Msave;
    }
}

// ---------------------------------------------------------------------------
// Combine: out[b] = log( sum_n w_tm[n] * beta[n] ) + Mf + Mb
// ---------------------------------------------------------------------------
__global__ __launch_bounds__(64)
void crf_combine_kernel(const float* __restrict__ wsW,
                        const float* __restrict__ wsU,
                        const float* __restrict__ wsMf,
                        const float* __restrict__ wsMb,
                        float* __restrict__ out) {
    const int b = blockIdx.x;
    const int l = threadIdx.x;
    const float* w = wsW + b * Nq;
    const float* u = wsU + b * Nq;
    float z = w[l] * u[l] + w[l + 64] * u[l + 64];
    #pragma unroll
    for (int off = 32; off >= 1; off >>= 1)
        z += __shfl_xor(z, off, 64);
    if (l == 0) out[b] = __logf(z) + wsMf[b] + wsMb[b];
}

extern "C" void kernel_launch(void* const* d_in, const int* in_sizes, int n_in,
                              void* d_out, int out_size, void* d_ws, size_t ws_size,
                              hipStream_t stream) {
    const float* emissions   = (const float*)d_in[0];
    const int*   token_sizes = (const int*)d_in[1];
    const int*   targets     = (const int*)d_in[2];
    const float* transitions = (const float*)d_in[3];  // (1,1,128,128)
    const float* head        = (const float*)d_in[4];  // (1,1,128)
    const float* last        = (const float*)d_in[5];  // (1,1,128)
    float* out = (float*)d_out;                        // (2,64,1) flat

    float* wsW  = (float*)d_ws;                  // 64*128 f32
    float* wsU  = wsW + Bq * Nq;                 // 64*128 f32
    float* wsMf = wsU + Bq * Nq;                 // 64
    float* wsMb = wsMf + Bq;                     // 64

    crf_kernel<<<3 * Bq, 128, 0, stream>>>(emissions, token_sizes, targets,
                                           transitions, head, last,
                                           wsW, wsU, wsMf, wsMb, out);
    crf_combine_kernel<<<Bq, 64, 0, stream>>>(wsW, wsU, wsMf, wsMb, out);
}

// Round 15
// 79.613 us; speedup vs baseline: 2.7761x; 2.2390x over previous
//
#include <hip/hip_runtime.h>
#include <math.h>

#define Bq 64
#define Tq 1024
#define Nq 128
#define SEG 16               // segments per chain
#define NFW (SEG - 1)        // forward workers: s = 1..SEG-1
#define NBW (SEG - 1)        // backward workers: s = 2..SEG
#define WK (NFW + NBW)       // 30 workers per chain

typedef __attribute__((ext_vector_type(2))) _Float16 h2;

#if defined(__has_builtin)
#  if __has_builtin(__builtin_amdgcn_fdot2)
#    define HAVE_FDOT2 1
#  endif
#  if __has_builtin(__builtin_amdgcn_rcpf)
#    define HAVE_RCPF 1
#  endif
#endif

__device__ __forceinline__ float dot2acc(h2 a, h2 b, float c) {
#ifdef HAVE_FDOT2
    return __builtin_amdgcn_fdot2(a, b, c, false);
#else
    return c + (float)a.x * (float)b.x + (float)a.y * (float)b.y;
#endif
}

__device__ __forceinline__ float fastrcp(float x) {
#ifdef HAVE_RCPF
    return __builtin_amdgcn_rcpf(x);
#else
    return 1.0f / x;
#endif
}

union Q16 { int4 v; h2 p[4]; };

#define EXP_NEG7 9.118819655545162e-4f

// ---------------------------------------------------------------------------
// One recursion step — R12/R14-proven body, direction-agnostic (absmax 0.0).
// ---------------------------------------------------------------------------
__device__ __forceinline__ void step_core(
    int rawRow, int n, const float* __restrict__ em_n,
    const _Float16* __restrict__ rb, _Float16* __restrict__ wb,
    const h2 (&e)[64],
    float& ee0, float& ee1, float& ee2, float& raw3, float& raw4,
    float& Mcur, float& pOut, float& ssOut)
{
    __syncthreads();                       // rb fully written

    // issue emission load for a step 5 ahead
    const float raw5 = em_n[(size_t)rawRow * Nq];

    const int4* p4 = (const int4*)rb;
    Q16 U[16];
    #pragma unroll
    for (int q = 0; q < 16; ++q) U[q].v = p4[q];     // broadcast reads
    asm volatile("" ::: "memory");         // keep wb store below the reads

    // sampled max of p[0..3] — identical in every lane (broadcast values)
    float pm = fmaxf(fmaxf((float)U[0].p[0].x, (float)U[0].p[0].y),
                     fmaxf((float)U[0].p[1].x, (float)U[0].p[1].y));
    pm = fmaxf(pm, 1e-6f);
    const float f = ee0 * (fastrcp(pm) * EXP_NEG7);

    float s[4] = {0.f, 0.f, 0.f, 0.f};
    #pragma unroll
    for (int j = 0; j < 64; ++j)                     // static after unroll
        s[j & 3] = dot2acc(U[j >> 2].p[j & 3], e[j], s[j & 3]);
    const float ss = (s[0] + s[1]) + (s[2] + s[3]);
    ssOut = ss;

    const float pn = fminf(ss * f, 60000.0f);
    wb[n] = (_Float16)pn;
    pOut = pn;

    // side chains (loop-carried only on themselves)
    Mcur += __logf(pm) + 7.0f;
    const float eeN = __expf(raw3);        // raw3 was loaded 3 steps ago
    ee0 = ee1; ee1 = ee2; ee2 = eeN;
    raw3 = raw4; raw4 = raw5;
}

// ---------------------------------------------------------------------------
// Workers: bid in [0, Bq*WK): chain b = bid/WK, worker w = bid%WK.
//   w in [0, NFW)       : FORWARD segment s = w+1     (a_s = M_s v; v = w0 if
//                         s==1 else ones-probe)
//   w in [NFW, WK)      : BACKWARD segment s = w-NFW+2 (b_s = M_s^T r; r = l if
//                         s==SEG else ones-probe)
// bid >= Bq*WK: gold-path score for chain (bid - Bq*WK).
// Segment s covers steps [lo_s, hi_s] of 1..tsz-1 (even split).
// ---------------------------------------------------------------------------
__global__ __launch_bounds__(128, 1)
void crf_worker_kernel(const float* __restrict__ emissions,
                       const int* __restrict__ token_sizes,
                       const int* __restrict__ targets,
                       const float* __restrict__ transitions,
                       const float* __restrict__ head,
                       const float* __restrict__ last,
                       float* __restrict__ wsA,    // [NFW][Bq][Nq]
                       float* __restrict__ wsB,    // [NBW][Bq][Nq]
                       float* __restrict__ wsLa,   // [NFW][Bq]
                       float* __restrict__ wsLb,   // [NBW][Bq]
                       float* __restrict__ out) {
    const int tid = threadIdx.x;
    const int bid = blockIdx.x;

    if (bid >= Bq * WK) {
        // ---------------- score path ----------------
        const int b = bid - Bq * WK;
        const int tsz = token_sizes[b];
        const int* tg = targets + b * Tq;
        const float* em = emissions + (size_t)b * Tq * Nq;
        float sc = 0.f;
        for (int t = tid; t < tsz; t += 128) {
            int cur = tg[t];
            sc += em[(size_t)t * Nq + cur];
            if (t >= 1) sc += transitions[tg[t - 1] * Nq + cur];
        }
        #pragma unroll
        for (int off = 32; off >= 1; off >>= 1)
            sc += __shfl_xor(sc, off, 64);
        __shared__ float wsum[2];
        if ((tid & 63) == 0) wsum[tid >> 6] = sc;
        __syncthreads();
        if (tid == 0)
            out[Bq + b] = wsum[0] + wsum[1] + head[tg[0]] + last[tg[tsz - 1]];
        return;
    }

    const int b = bid / WK;
    const int w = bid % WK;
    const bool isFwd = (w < NFW);
    const int s = isFwd ? (w + 1) : (w - NFW + 2);

    const int n = tid;
    const int wv = tid >> 6;
    const int l = tid & 63;
    const float* em_c = emissions + (size_t)b * Tq * Nq;
    const float* em_n = em_c + n;
    const int tsz = token_sizes[b];          // in [T/2, T]

    // segment bounds over steps 1..tsz-1
    const int nst = tsz - 1;
    const int base = nst / SEG;
    const int rem = nst % SEG;
    const int lo = 1 + (s - 1) * base + min(s - 1, rem);
    const int len = base + ((s <= rem) ? 1 : 0);   // >= 31 for tsz >= 512
    const int hi = lo + len - 1;

    __shared__ __align__(16) _Float16 pbuf[2][Nq];
    __shared__ float redA[2];

    // E fragments: forward = column n of E; backward = row n of E.
    h2 e[64];
    if (isFwd) {
        #pragma unroll
        for (int j = 0; j < 64; ++j) {
            h2 v;
            v.x = (_Float16)__expf(transitions[(2 * j)     * Nq + n]);
            v.y = (_Float16)__expf(transitions[(2 * j + 1) * Nq + n]);
            e[j] = v;
        }
    } else {
        #pragma unroll
        for (int j = 0; j < 64; ++j) {
            h2 v;
            v.x = (_Float16)__expf(transitions[n * Nq + 2 * j]);
            v.y = (_Float16)__expf(transitions[n * Nq + 2 * j + 1]);
            e[j] = v;
        }
    }
    #pragma unroll
    for (int j = 0; j < 64; ++j) asm volatile("" : "+v"(e[j]));

    // init vector (log domain): true init at the chain ends, ones-probe inside
    float v0;
    if (isFwd) v0 = (s == 1) ? (head[n] + em_n[0]) : 0.0f;
    else       v0 = ((s == SEG) ? last[n] : 0.0f) + em_n[(size_t)hi * Nq];

    float Mcur;
    {
        float wr = v0;
        #pragma unroll
        for (int off = 32; off >= 1; off >>= 1)
            wr = fmaxf(wr, __shfl_xor(wr, off, 64));
        if (l == 0) redA[wv] = wr;
        __syncthreads();
        Mcur = fmaxf(redA[0], redA[1]);
    }
    pbuf[0][n] = (_Float16)__expf(v0 - Mcur);   // in (0,1]

    // emission pipeline (rows lo.. ascending for fwd, hi-1.. descending for bwd)
    float ee0, ee1, ee2, raw3, raw4;
    if (isFwd) {
        ee0 = __expf(em_n[(size_t)(lo)     * Nq]);
        ee1 = __expf(em_n[(size_t)(lo + 1) * Nq]);
        ee2 = __expf(em_n[(size_t)(lo + 2) * Nq]);
        raw3 = em_n[(size_t)(lo + 3) * Nq];
        raw4 = em_n[(size_t)(lo + 4) * Nq];
    } else {
        ee0 = __expf(em_n[(size_t)(hi - 1) * Nq]);
        ee1 = __expf(em_n[(size_t)(hi - 2) * Nq]);
        ee2 = __expf(em_n[(size_t)(hi - 3) * Nq]);
        raw3 = em_n[(size_t)(hi - 4) * Nq];
        raw4 = em_n[(size_t)(hi - 5) * Nq];
    }

    float pOut = 0.f, ssOut = 0.f, Msave = Mcur;
    _Float16* b0 = &pbuf[0][0];
    _Float16* b1 = &pbuf[1][0];

    // row fetched by body k (consumed 5 bodies later; over-segment loads are
    // never consumed, only clamped into the valid emission range)
    #define RAW_ROW(k) (isFwd ? min(lo + 4 + (k), tsz - 1) : max(hi - 5 - (k), 0))

    int k = 1;
    for (; k + 3 <= len; k += 4) {
        Msave = Mcur;
        step_core(RAW_ROW(k),     n, em_n, b0, b1, e, ee0, ee1, ee2, raw3, raw4, Mcur, pOut, ssOut);
        Msave = Mcur;
        step_core(RAW_ROW(k + 1), n, em_n, b1, b0, e, ee0, ee1, ee2, raw3, raw4, Mcur, pOut, ssOut);
        Msave = Mcur;
        step_core(RAW_ROW(k + 2), n, em_n, b0, b1, e, ee0, ee1, ee2, raw3, raw4, Mcur, pOut, ssOut);
        Msave = Mcur;
        step_core(RAW_ROW(k + 3), n, em_n, b1, b0, e, ee0, ee1, ee2, raw3, raw4, Mcur, pOut, ssOut);
    }
    if (k <= len) {
        Msave = Mcur;
        step_core(RAW_ROW(k), n, em_n, b0, b1, e, ee0, ee1, ee2, raw3, raw4, Mcur, pOut, ssOut);
        ++k;
        if (k <= len) {
            Msave = Mcur;
            step_core(RAW_ROW(k), n, em_n, b1, b0, e, ee0, ee1, ee2, raw3, raw4, Mcur, pOut, ssOut);
            ++k;
            if (k <= len) {
                Msave = Mcur;
                step_core(RAW_ROW(k), n, em_n, b0, b1, e, ee0, ee1, ee2, raw3, raw4, Mcur, pOut, ssOut);
            }
        }
    }
    #undef RAW_ROW

    if (isFwd) {
        // a_s = pOut * e^{Mcur}  (post-update ledger pairing, R12-proven)
        wsA[((size_t)(s - 1) * Bq + b) * Nq + n] = pOut;
        if (tid == 0) wsLa[(s - 1) * Bq + b] = Mcur;
    } else {
        // b_s = ssOut * e^{Msave} (pre-update ledger pairing, R12-proven)
        wsB[((size_t)(s - 2) * Bq + b) * Nq + n] = ssOut;
        if (tid == 0) wsLb[(s - 2) * Bq + b] = Msave;
    }
}

// ---------------------------------------------------------------------------
// Combine (rank-1 chain):
// logZ = log(b_S . a_{S-1}) + Lb[S] + La[S-1]
//      + sum_{s=2}^{S-1} [ log(b_s . a_{s-1}) + La[s-1] - log(sum(b_s)) ]
// ---------------------------------------------------------------------------
__global__ __launch_bounds__(64)
void crf_combine_kernel(const float* __restrict__ wsA,
                        const float* __restrict__ wsB,
                        const float* __restrict__ wsLa,
                        const float* __restrict__ wsLb,
                        float* __restrict__ out) {
    const int b = blockIdx.x;
    const int l = threadIdx.x;

    float total;
    {   // top junction: b_SEG . a_{SEG-1}
        const float* bb = wsB + ((size_t)(SEG - 2) * Bq + b) * Nq;
        const float* aa = wsA + ((size_t)(SEG - 2) * Bq + b) * Nq;
        float z = bb[l] * aa[l] + bb[l + 64] * aa[l + 64];
        #pragma unroll
        for (int off = 32; off >= 1; off >>= 1)
            z += __shfl_xor(z, off, 64);
        total = __logf(z) + wsLb[(SEG - 2) * Bq + b] + wsLa[(SEG - 2) * Bq + b];
    }
    for (int s = 2; s <= SEG - 1; ++s) {
        const float* bb = wsB + ((size_t)(s - 2) * Bq + b) * Nq;
        const float* aa = wsA + ((size_t)(s - 2) * Bq + b) * Nq;  // a_{s-1}
        float z = bb[l] * aa[l] + bb[l + 64] * aa[l + 64];
        float c = bb[l] + bb[l + 64];
        #pragma unroll
        for (int off = 32; off >= 1; off >>= 1) {
            z += __shfl_xor(z, off, 64);
            c += __shfl_xor(c, off, 64);
        }
        total += __logf(z) + wsLa[(s - 2) * Bq + b] - __logf(c);
    }
    if (l == 0) out[b] = total;
}

extern "C" void kernel_launch(void* const* d_in, const int* in_sizes, int n_in,
                              void* d_out, int out_size, void* d_ws, size_t ws_size,
                              hipStream_t stream) {
    const float* emissions   = (const float*)d_in[0];
    const int*   token_sizes = (const int*)d_in[1];
    const int*   targets     = (const int*)d_in[2];
    const float* transitions = (const float*)d_in[3];  // (1,1,128,128)
    const float* head        = (const float*)d_in[4];  // (1,1,128)
    const float* last        = (const float*)d_in[5];  // (1,1,128)
    float* out = (float*)d_out;                        // (2,64,1) flat

    float* wsA  = (float*)d_ws;                        // NFW*Bq*Nq
    float* wsB  = wsA + (size_t)NFW * Bq * Nq;         // NBW*Bq*Nq
    float* wsLa = wsB + (size_t)NBW * Bq * Nq;         // NFW*Bq
    float* wsLb = wsLa + NFW * Bq;                     // NBW*Bq

    crf_worker_kernel<<<Bq * WK + Bq, 128, 0, stream>>>(
        emissions, token_sizes, targets, transitions, head, last,
        wsA, wsB, wsLa, wsLb, out);
    crf_combine_kernel<<<Bq, 64, 0, stream>>>(wsA, wsB, wsLa, wsLb, out);
}